// Round 4
// baseline (225.344 us; speedup 1.0000x reference)
//
#include <hip/hip_runtime.h>
#include <cstdint>
#include <cstddef>

// Problem constants (fixed by the reference)
#define N_ROWS 4096
#define DIM    512
#define NCLS   30000
#define BM 256
#define BN 256
#define BK 32
#define NT2  118                    // ceil(30000/256) N-tiles
#define CPAD (NT2 * 256)            // 30208, padded classes (zero rows)
#define SPT 2                       // N-tiles per block strip
#define NSTRIPS (NT2 / SPT)         // 59
#define KT  (DIM / BK)              // 16 K-steps per N-tile
#define NS  (SPT * KT)              // 32 K-steps per block

typedef float  f32x4  __attribute__((ext_vector_type(4)));
typedef short  bf16x8 __attribute__((ext_vector_type(8)));
typedef unsigned int   u32;
typedef unsigned short u16;

// ---- workspace layout (bytes) ----
#define WB_BYTES   ((size_t)CPAD * DIM * 2)     // 30,932,992
#define EB_BYTES   ((size_t)N_ROWS * DIM * 2)   //  4,194,304
#define PS_BYTES   ((size_t)NT2 * N_ROWS * 4)   //  1,933,312
#define CT_BYTES   ((size_t)N_ROWS * 4)
#define BL_BYTES   (64 * 4)
#define LAB_BYTES  ((size_t)N_ROWS * 4)

#define CLIP_HI ( 1.0f - 1e-7f)
#define CLIP_LO (-1.0f + 1e-7f)
#define COSM 0.8775825618903728f    // cos(0.5)
#define SINM 0.4794255386042030f    // sin(0.5)
#define K1   92.33248261972189f     // 64*log2(e): exp(64c-64) = 2^((c-1)*K1)

__device__ __forceinline__ u16 f2bf(float f) {  // RNE float->bf16
  u32 x = __builtin_bit_cast(u32, f);
  x += 0x7fffu + ((x >> 16) & 1u);
  return (u16)(x >> 16);
}

__device__ __forceinline__ void gl_lds16(const u16* g, u16* l) {
  __builtin_amdgcn_global_load_lds((const __attribute__((address_space(1))) u32*)g,
                                   (__attribute__((address_space(3))) u32*)l,
                                   16, 0, 0);
}

// ---- label dtype probe: int64 little-endian reads as [lo,0,lo,0,...] ----
__global__ void lab_detect(const int* __restrict__ lab, int* __restrict__ flag) {
  __shared__ int s_nz;
  int tid = threadIdx.x;
  if (tid == 0) s_nz = 0;
  __syncthreads();
  int nz = 0;
  for (int i = tid; i < N_ROWS / 2; i += 1024) nz |= lab[2 * i + 1];
  if (nz) atomicOr(&s_nz, 1);
  __syncthreads();
  if (tid == 0) *flag = (s_nz == 0) ? 1 : 0;   // 1 -> int64 layout
}

__global__ void lab_fix(const int* __restrict__ lab, const int* __restrict__ flag,
                        int* __restrict__ out) {
  int i = blockIdx.x * 256 + threadIdx.x;
  out[i] = flag[0] ? lab[2 * i] : lab[i];
}

// ---- W: L2-normalize rows + cast bf16; pad rows [NCLS,CPAD) with zeros ----
__global__ void prep_w(const float* __restrict__ w, u16* __restrict__ wb) {
  int wv   = threadIdx.x >> 6;
  int lane = threadIdx.x & 63;
  int c = blockIdx.x * 4 + wv;              // one wave per class row
  u16* dst = wb + (size_t)c * DIM + lane * 8;
  if (c >= NCLS) {
    *(uint4*)dst = make_uint4(0, 0, 0, 0);
    return;
  }
  const float* src = w + (size_t)c * DIM + lane * 8;
  float4 v0 = *(const float4*)src;
  float4 v1 = *(const float4*)(src + 4);
  float a[8] = {v0.x, v0.y, v0.z, v0.w, v1.x, v1.y, v1.z, v1.w};
  float ss = 0.f;
  #pragma unroll
  for (int i = 0; i < 8; i++) ss += a[i] * a[i];
  #pragma unroll
  for (int off = 32; off; off >>= 1) ss += __shfl_xor(ss, off, 64);
  float inv = 1.0f / fmaxf(sqrtf(ss), 1e-12f);
  union { u16 h[8]; uint4 q; } pk;
  #pragma unroll
  for (int i = 0; i < 8; i++) pk.h[i] = f2bf(a[i] * inv);
  *(uint4*)dst = pk.q;
}

// ---- E: cast bf16 ----
__global__ void prep_e(const float* __restrict__ e, u16* __restrict__ eb) {
  size_t idx = ((size_t)blockIdx.x * 256 + threadIdx.x) * 8;
  float4 v0 = *(const float4*)(e + idx);
  float4 v1 = *(const float4*)(e + idx + 4);
  float a[8] = {v0.x, v0.y, v0.z, v0.w, v1.x, v1.y, v1.z, v1.w};
  union { u16 h[8]; uint4 q; } pk;
  #pragma unroll
  for (int i = 0; i < 8; i++) pk.h[i] = f2bf(a[i]);
  *(uint4*)(eb + idx) = pk.q;
}

// ---- target cosine per row, f32: dot(emb[n], w[lab[n]]/||w[lab[n]]||) ----
__global__ void tgt_k(const float* __restrict__ emb, const float* __restrict__ wts,
                      const int* __restrict__ lab, float* __restrict__ ct) {
  int w = threadIdx.x >> 6, l = threadIdx.x & 63;
  int row = blockIdx.x * 4 + w;
  int c = lab[row];
  const float* e  = emb + (size_t)row * DIM + l * 8;
  const float* wp = wts + (size_t)c   * DIM + l * 8;
  float4 e0 = *(const float4*)e,       e1 = *(const float4*)(e + 4);
  float4 w0 = *(const float4*)wp,      w1 = *(const float4*)(wp + 4);
  float dot = e0.x*w0.x + e0.y*w0.y + e0.z*w0.z + e0.w*w0.w
            + e1.x*w1.x + e1.y*w1.y + e1.z*w1.z + e1.w*w1.w;
  float ss  = w0.x*w0.x + w0.y*w0.y + w0.z*w0.z + w0.w*w0.w
            + w1.x*w1.x + w1.y*w1.y + w1.z*w1.z + w1.w*w1.w;
  #pragma unroll
  for (int off = 32; off; off >>= 1) {
    dot += __shfl_xor(dot, off, 64);
    ss  += __shfl_xor(ss,  off, 64);
  }
  if (l == 0) ct[row] = dot / fmaxf(sqrtf(ss), 1e-12f);
}

// ---- fused GEMM + clip + partial sum-exp (fixed max = 64), 256x256 tile ----
// 8 waves (2m x 4n); 3-buffer ring, stage 2 K-steps ahead, uniform vmcnt(4)
// once per K-step; each K-step split into 4 fine phases:
//   {ds_reads + 1 stage gl_lds; s_barrier; lgkmcnt(0)+sched_barrier;
//    setprio(1) 8xMFMA setprio(0); s_barrier}
__global__ __launch_bounds__(512, 2) void arc_main(
    const u16* __restrict__ eb, const u16* __restrict__ wb,
    float* __restrict__ psum)
{
  __shared__ __align__(16) u16 lds[6 * 8192];   // 3xA + 3xB tiles (16 KB each) = 96 KB
  __shared__ float ep[4][BM];
  const int tid = threadIdx.x;
  const int l   = tid & 63;
  const int w   = tid >> 6;
  const int wm  = w >> 2, wn = w & 3;
  const int mi    = blockIdx.x & 15;    // m inner: concurrent blocks share E in L3
  const int strip = blockIdx.x >> 4;
  const int rowbase = mi * BM;
  const int n0s = strip * SPT;

  // frag LDS elem offsets; 16B-slot swizzle b' = b ^ ((r>>1)&3) -> 2-way (free)
  u32 aoff[8], boff[4];
  const int bq = l >> 4;
  #pragma unroll
  for (int m = 0; m < 8; m++) {
    int r = wm * 128 + m * 16 + (l & 15);
    aoff[m] = (u32)r * BK + ((bq ^ ((r >> 1) & 3)) << 3);
  }
  #pragma unroll
  for (int n = 0; n < 4; n++) {
    int r = wn * 64 + n * 16 + (l & 15);
    boff[n] = (u32)r * BK + ((bq ^ ((r >> 1) & 3)) << 3);
  }

  // staging: all 512 threads cover one 8 KB half-tile per gl_lds round;
  // linear LDS dest + inverse-swizzled global source (same involution).
  u32 goff[2];
  #pragma unroll
  for (int c = 0; c < 2; c++) {
    int rl = c * 128 + (tid >> 2);
    goff[c] = (u32)rl * DIM + (((tid & 3) ^ ((rl >> 1) & 3)) << 3);
  }
  const u16* ebR = eb + (size_t)rowbase * DIM;

  u16 *pA = lds,             *qA = lds + 8192,  *sA = lds + 16384;
  u16 *pB = lds + 24576,     *qB = lds + 32768, *sB = lds + 40960;

  #define STAGE_A(v_, t_, c_) \
    gl_lds16(ebR + (u32)(((v_) & 15) * BK) + goff[c_], (t_) + (c_) * 4096 + w * 512)
  #define STAGE_B(v_, t_, c_) \
    gl_lds16(wb + (u32)(n0s + ((v_) >> 4)) * (BN * DIM) + (u32)(((v_) & 15) * BK) + goff[c_], \
             (t_) + (c_) * 4096 + w * 512)

  f32x4 acc[8][4];
  #pragma unroll
  for (int m = 0; m < 8; m++)
    #pragma unroll
    for (int n = 0; n < 4; n++)
      #pragma unroll
      for (int q = 0; q < 4; q++) acc[m][n][q] = 0.f;

  // prologue: stage K-steps 0 and 1 (4 chunks each, issue order = ring order)
  STAGE_A(0, pA, 0); STAGE_A(0, pA, 1); STAGE_B(0, pB, 0); STAGE_B(0, pB, 1);
  STAGE_A(1, qA, 0); STAGE_A(1, qA, 1); STAGE_B(1, qB, 0); STAGE_B(1, qB, 1);

  for (int u = 0; u < NS; u++) {
    const bool st = (u + 2 < NS);
    bf16x8 afv[4], bgv[4];

    // ---- phase 0: af[0-3], bg[0-1]; stage A-c0(u+2); MFMA m0-3 x n0-1 ----
    if (u < NS - 1) asm volatile("s_waitcnt vmcnt(4)" ::: "memory");
    else            asm volatile("s_waitcnt vmcnt(0)" ::: "memory");
    #pragma unroll
    for (int m = 0; m < 4; m++) afv[m] = *(const bf16x8*)&pA[aoff[m]];
    bgv[0] = *(const bf16x8*)&pB[boff[0]];
    bgv[1] = *(const bf16x8*)&pB[boff[1]];
    if (st) STAGE_A(u + 2, sA, 0);
    __builtin_amdgcn_s_barrier();
    asm volatile("s_waitcnt lgkmcnt(0)" ::: "memory");
    __builtin_amdgcn_sched_barrier(0);
    __builtin_amdgcn_s_setprio(1);
    #pragma unroll
    for (int m = 0; m < 4; m++)
      #pragma unroll
      for (int n = 0; n < 2; n++)
        acc[m][n] = __builtin_amdgcn_mfma_f32_16x16x32_bf16(afv[m], bgv[n], acc[m][n], 0, 0, 0);
    __builtin_amdgcn_s_setprio(0);
    __builtin_amdgcn_sched_barrier(0);
    __builtin_amdgcn_s_barrier();

    // ---- phase 1: bg[2-3]; stage A-c1(u+2); MFMA m0-3 x n2-3 ----
    bgv[2] = *(const bf16x8*)&pB[boff[2]];
    bgv[3] = *(const bf16x8*)&pB[boff[3]];
    if (st) STAGE_A(u + 2, sA, 1);
    __builtin_amdgcn_s_barrier();
    asm volatile("s_waitcnt lgkmcnt(0)" ::: "memory");
    __builtin_amdgcn_sched_barrier(0);
    __builtin_amdgcn_s_setprio(1);
    #pragma unroll
    for (int m = 0; m < 4; m++)
      #pragma unroll
      for (int n = 2; n < 4; n++)
        acc[m][n] = __builtin_amdgcn_mfma_f32_16x16x32_bf16(afv[m], bgv[n], acc[m][n], 0, 0, 0);
    __builtin_amdgcn_s_setprio(0);
    __builtin_amdgcn_sched_barrier(0);
    __builtin_amdgcn_s_barrier();

    // ---- phase 2: af[4-7]; stage B-c0(u+2); MFMA m4-7 x n0-1 ----
    #pragma unroll
    for (int m = 0; m < 4; m++) afv[m] = *(const bf16x8*)&pA[aoff[m + 4]];
    if (st) STAGE_B(u + 2, sB, 0);
    __builtin_amdgcn_s_barrier();
    asm volatile("s_waitcnt lgkmcnt(0)" ::: "memory");
    __builtin_amdgcn_sched_barrier(0);
    __builtin_amdgcn_s_setprio(1);
    #pragma unroll
    for (int m = 0; m < 4; m++)
      #pragma unroll
      for (int n = 0; n < 2; n++)
        acc[m + 4][n] = __builtin_amdgcn_mfma_f32_16x16x32_bf16(afv[m], bgv[n], acc[m + 4][n], 0, 0, 0);
    __builtin_amdgcn_s_setprio(0);
    __builtin_amdgcn_sched_barrier(0);
    __builtin_amdgcn_s_barrier();

    // ---- phase 3: no reads; stage B-c1(u+2); MFMA m4-7 x n2-3 ----
    if (st) STAGE_B(u + 2, sB, 1);
    __builtin_amdgcn_s_barrier();
    __builtin_amdgcn_sched_barrier(0);
    __builtin_amdgcn_s_setprio(1);
    #pragma unroll
    for (int m = 0; m < 4; m++)
      #pragma unroll
      for (int n = 2; n < 4; n++)
        acc[m + 4][n] = __builtin_amdgcn_mfma_f32_16x16x32_bf16(afv[m], bgv[n], acc[m + 4][n], 0, 0, 0);
    __builtin_amdgcn_s_setprio(0);
    __builtin_amdgcn_sched_barrier(0);
    __builtin_amdgcn_s_barrier();

    if ((u & 15) == 15) {
      // epilogue for N-tile nt: clip, exp2, sum over wave's 64 cols,
      // cross-wn merge via LDS, one psum row-partial per N-tile.
      const int nt = n0s + (u >> 4);
      #pragma unroll
      for (int m = 0; m < 8; m++) {
        #pragma unroll
        for (int q = 0; q < 4; q++) {
          float s = 0.f;
          #pragma unroll
          for (int n = 0; n < 4; n++) {
            float tc = __builtin_amdgcn_fmed3f(acc[m][n][q], CLIP_LO, CLIP_HI);
            s += __builtin_amdgcn_exp2f(__builtin_fmaf(tc, K1, -K1));
            acc[m][n][q] = 0.f;
          }
          s += __shfl_xor(s, 1, 64);
          s += __shfl_xor(s, 2, 64);
          s += __shfl_xor(s, 4, 64);
          s += __shfl_xor(s, 8, 64);
          if ((l & 15) == 0) ep[wn][wm * 128 + m * 16 + (l >> 4) * 4 + q] = s;
        }
      }
      asm volatile("s_waitcnt lgkmcnt(0)" ::: "memory");
      __builtin_amdgcn_s_barrier();
      asm volatile("" ::: "memory");
      if (l < 32) {
        int r = w * 32 + l;
        float t = ep[0][r] + ep[1][r] + ep[2][r] + ep[3][r];
        psum[(size_t)nt * N_ROWS + rowbase + r] = t;
      }
      __builtin_amdgcn_s_barrier();   // ep reads done before next tile's writes
    }

    u16* t0 = pA; pA = qA; qA = sA; sA = t0;
    u16* t1 = pB; pB = qB; qB = sB; sB = t1;
  }
  #undef STAGE_A
  #undef STAGE_B
}

// ---- per-row LSE merge + margin swap + per-block loss sums ----
__global__ void arc_finish1(const float* __restrict__ psum, const float* __restrict__ ct,
                            float* __restrict__ bl) {
  int tid = threadIdx.x;
  int row = blockIdx.x * 256 + tid;
  float S = 0.f;
  for (int p = 0; p < NT2; p++) S += psum[(size_t)p * N_ROWS + row];
  float c  = __builtin_amdgcn_fmed3f(ct[row], CLIP_LO, CLIP_HI);
  float cm = c * COSM - sqrtf(fmaxf(1.0f - c * c, 0.0f)) * SINM;
  // swap the target's no-margin term for the margin term (both vs fixed max 64)
  float S2 = S - __builtin_amdgcn_exp2f(__builtin_fmaf(c,  K1, -K1))
               + __builtin_amdgcn_exp2f(__builtin_fmaf(cm, K1, -K1));
  float loss = 64.0f + __builtin_amdgcn_logf(S2) * 0.6931471805599453f - 64.0f * cm;
  #pragma unroll
  for (int off = 32; off; off >>= 1) loss += __shfl_xor(loss, off, 64);
  __shared__ float red[4];
  if ((tid & 63) == 0) red[tid >> 6] = loss;
  __syncthreads();
  if (tid == 0) bl[blockIdx.x] = red[0] + red[1] + red[2] + red[3];
}

__global__ void arc_finish2(const float* __restrict__ bl, float* __restrict__ out) {
  if (threadIdx.x == 0) {
    float t = 0.f;
    for (int i = 0; i < N_ROWS / 256; i++) t += bl[i];
    out[0] = t * (1.0f / (float)N_ROWS);
  }
}

extern "C" void kernel_launch(void* const* d_in, const int* in_sizes, int n_in,
                              void* d_out, int out_size, void* d_ws, size_t ws_size,
                              hipStream_t stream) {
  const float* emb   = (const float*)d_in[0];
  const int*   lab   = (const int*)d_in[1];
  const float* wts   = (const float*)d_in[2];

  char* ws = (char*)d_ws;
  u16*   wb    = (u16*)(ws);
  u16*   eb    = (u16*)(ws + WB_BYTES);
  float* psum  = (float*)(ws + WB_BYTES + EB_BYTES);
  float* ct    = (float*)(ws + WB_BYTES + EB_BYTES + PS_BYTES);
  float* bl    = (float*)(ws + WB_BYTES + EB_BYTES + PS_BYTES + CT_BYTES);
  int*   lab32 = (int*)  (ws + WB_BYTES + EB_BYTES + PS_BYTES + CT_BYTES + BL_BYTES);
  int*   flag  = (int*)  (ws + WB_BYTES + EB_BYTES + PS_BYTES + CT_BYTES + BL_BYTES + LAB_BYTES);
  // total ~37.1 MiB of d_ws assumed available

  lab_detect<<<dim3(1), dim3(1024), 0, stream>>>(lab, flag);
  lab_fix<<<dim3(N_ROWS / 256), dim3(256), 0, stream>>>(lab, flag, lab32);
  prep_w<<<dim3(CPAD / 4), dim3(256), 0, stream>>>(wts, wb);
  prep_e<<<dim3((N_ROWS * DIM / 8) / 256), dim3(256), 0, stream>>>(emb, eb);
  tgt_k<<<dim3(N_ROWS / 4), dim3(256), 0, stream>>>(emb, wts, lab32, ct);
  arc_main<<<dim3(16 * NSTRIPS), dim3(512), 0, stream>>>(eb, wb, psum);
  arc_finish1<<<dim3(N_ROWS / 256), dim3(256), 0, stream>>>(psum, ct, bl);
  arc_finish2<<<dim3(1), dim3(64), 0, stream>>>(bl, (float*)d_out);
}

// Round 5
// 211.067 us; speedup vs baseline: 1.0676x; 1.0676x over previous
//
#include <hip/hip_runtime.h>
#include <cstdint>
#include <cstddef>

// Problem constants (fixed by the reference)
#define N_ROWS 4096
#define DIM    512
#define NCLS   30000
#define BM 256
#define BN 256
#define BK 32
#define NT2  118                    // ceil(30000/256) N-tiles
#define CPAD (NT2 * 256)            // 30208, padded classes (zero rows)
#define SPT 2                       // N-tiles per block strip
#define NSTRIPS (NT2 / SPT)         // 59
#define KT  (DIM / BK)              // 16 K-steps per N-tile
#define NS  (SPT * KT)              // 32 K-steps per block

typedef float  f32x4  __attribute__((ext_vector_type(4)));
typedef short  bf16x8 __attribute__((ext_vector_type(8)));
typedef unsigned int   u32;
typedef unsigned short u16;

// ---- workspace layout (bytes) ----
#define WB_BYTES   ((size_t)CPAD * DIM * 2)     // 30,932,992
#define EB_BYTES   ((size_t)N_ROWS * DIM * 2)   //  4,194,304
#define PS_BYTES   ((size_t)NT2 * N_ROWS * 4)   //  1,933,312
#define CT_BYTES   ((size_t)N_ROWS * 4)
#define BL_BYTES   (64 * 4)
#define LAB_BYTES  ((size_t)N_ROWS * 4)

#define CLIP_HI ( 1.0f - 1e-7f)
#define CLIP_LO (-1.0f + 1e-7f)
#define COSM 0.8775825618903728f    // cos(0.5)
#define SINM 0.4794255386042030f    // sin(0.5)
#define K1   92.33248261972189f     // 64*log2(e): exp(64c-64) = 2^((c-1)*K1)

__device__ __forceinline__ u16 f2bf(float f) {  // RNE float->bf16
  u32 x = __builtin_bit_cast(u32, f);
  x += 0x7fffu + ((x >> 16) & 1u);
  return (u16)(x >> 16);
}

__device__ __forceinline__ void gl_lds16(const u16* g, u16* l) {
  __builtin_amdgcn_global_load_lds((const __attribute__((address_space(1))) u32*)g,
                                   (__attribute__((address_space(3))) u32*)l,
                                   16, 0, 0);
}

// ---- label dtype probe: int64 little-endian reads as [lo,0,lo,0,...] ----
__global__ void lab_detect(const int* __restrict__ lab, int* __restrict__ flag) {
  __shared__ int s_nz;
  int tid = threadIdx.x;
  if (tid == 0) s_nz = 0;
  __syncthreads();
  int nz = 0;
  for (int i = tid; i < N_ROWS / 2; i += 1024) nz |= lab[2 * i + 1];
  if (nz) atomicOr(&s_nz, 1);
  __syncthreads();
  if (tid == 0) *flag = (s_nz == 0) ? 1 : 0;   // 1 -> int64 layout
}

__global__ void lab_fix(const int* __restrict__ lab, const int* __restrict__ flag,
                        int* __restrict__ out) {
  int i = blockIdx.x * 256 + threadIdx.x;
  out[i] = flag[0] ? lab[2 * i] : lab[i];
}

// ---- W: L2-normalize rows + cast bf16; pad rows [NCLS,CPAD) with zeros ----
__global__ void prep_w(const float* __restrict__ w, u16* __restrict__ wb) {
  int wv   = threadIdx.x >> 6;
  int lane = threadIdx.x & 63;
  int c = blockIdx.x * 4 + wv;              // one wave per class row
  u16* dst = wb + (size_t)c * DIM + lane * 8;
  if (c >= NCLS) {
    *(uint4*)dst = make_uint4(0, 0, 0, 0);
    return;
  }
  const float* src = w + (size_t)c * DIM + lane * 8;
  float4 v0 = *(const float4*)src;
  float4 v1 = *(const float4*)(src + 4);
  float a[8] = {v0.x, v0.y, v0.z, v0.w, v1.x, v1.y, v1.z, v1.w};
  float ss = 0.f;
  #pragma unroll
  for (int i = 0; i < 8; i++) ss += a[i] * a[i];
  #pragma unroll
  for (int off = 32; off; off >>= 1) ss += __shfl_xor(ss, off, 64);
  float inv = 1.0f / fmaxf(sqrtf(ss), 1e-12f);
  union { u16 h[8]; uint4 q; } pk;
  #pragma unroll
  for (int i = 0; i < 8; i++) pk.h[i] = f2bf(a[i] * inv);
  *(uint4*)dst = pk.q;
}

// ---- E: cast bf16 ----
__global__ void prep_e(const float* __restrict__ e, u16* __restrict__ eb) {
  size_t idx = ((size_t)blockIdx.x * 256 + threadIdx.x) * 8;
  float4 v0 = *(const float4*)(e + idx);
  float4 v1 = *(const float4*)(e + idx + 4);
  float a[8] = {v0.x, v0.y, v0.z, v0.w, v1.x, v1.y, v1.z, v1.w};
  union { u16 h[8]; uint4 q; } pk;
  #pragma unroll
  for (int i = 0; i < 8; i++) pk.h[i] = f2bf(a[i]);
  *(uint4*)(eb + idx) = pk.q;
}

// ---- target cosine per row, f32: dot(emb[n], w[lab[n]]/||w[lab[n]]||) ----
__global__ void tgt_k(const float* __restrict__ emb, const float* __restrict__ wts,
                      const int* __restrict__ lab, float* __restrict__ ct) {
  int w = threadIdx.x >> 6, l = threadIdx.x & 63;
  int row = blockIdx.x * 4 + w;
  int c = lab[row];
  const float* e  = emb + (size_t)row * DIM + l * 8;
  const float* wp = wts + (size_t)c   * DIM + l * 8;
  float4 e0 = *(const float4*)e,       e1 = *(const float4*)(e + 4);
  float4 w0 = *(const float4*)wp,      w1 = *(const float4*)(wp + 4);
  float dot = e0.x*w0.x + e0.y*w0.y + e0.z*w0.z + e0.w*w0.w
            + e1.x*w1.x + e1.y*w1.y + e1.z*w1.z + e1.w*w1.w;
  float ss  = w0.x*w0.x + w0.y*w0.y + w0.z*w0.z + w0.w*w0.w
            + w1.x*w1.x + w1.y*w1.y + w1.z*w1.z + w1.w*w1.w;
  #pragma unroll
  for (int off = 32; off; off >>= 1) {
    dot += __shfl_xor(dot, off, 64);
    ss  += __shfl_xor(ss,  off, 64);
  }
  if (l == 0) ct[row] = dot / fmaxf(sqrtf(ss), 1e-12f);
}

// ---- fused GEMM + clip + partial sum-exp (fixed max = 64), 256x256 tile ----
// 8 waves (2m x 4n); 3-buffer ring, stage 2 K-steps ahead, counted vmcnt(4);
// per K-step 2 phases of 16 MFMA (m-halves) with a pacing barrier between;
// no sched_barrier pinning (compiler keeps fine lgkmcnt interleave).
// XCD-chunked block remap: 944 = 8 x 118, each XCD gets contiguous tiles
// -> strip's B panel + E panel L2-resident per XCD.
__global__ __launch_bounds__(512, 1) void arc_main(
    const u16* __restrict__ eb, const u16* __restrict__ wb,
    float* __restrict__ psum)
{
  __shared__ __align__(16) u16 lds[6 * 8192];   // 3xA + 3xB tiles (16 KB each) = 96 KB
  __shared__ float ep[4][BM];
  const int tid = threadIdx.x;
  const int l   = tid & 63;
  const int w   = tid >> 6;
  const int wm  = w >> 2, wn = w & 3;

  // bijective XCD chunk remap (m204, r=0): HW round-robins bid%8 over XCDs.
  const int bid = blockIdx.x;
  const int wg  = (bid & 7) * (16 * NSTRIPS / 8) + (bid >> 3);
  const int mi    = wg & 15;          // m inner: XCD round covers all 16 mi
  const int strip = wg >> 4;
  const int rowbase = mi * BM;
  const int n0s = strip * SPT;

  // frag LDS elem offsets; 16B-slot swizzle b' = b ^ ((r>>1)&3) -> 2-way (free)
  u32 aoff[8], boff[4];
  const int bq = l >> 4;
  #pragma unroll
  for (int m = 0; m < 8; m++) {
    int r = wm * 128 + m * 16 + (l & 15);
    aoff[m] = (u32)r * BK + ((bq ^ ((r >> 1) & 3)) << 3);
  }
  #pragma unroll
  for (int n = 0; n < 4; n++) {
    int r = wn * 64 + n * 16 + (l & 15);
    boff[n] = (u32)r * BK + ((bq ^ ((r >> 1) & 3)) << 3);
  }

  // staging: all 512 threads cover one 8 KB half-tile per gl_lds round;
  // linear LDS dest + inverse-swizzled global source (same involution).
  u32 goff[2];
  #pragma unroll
  for (int c = 0; c < 2; c++) {
    int rl = c * 128 + (tid >> 2);
    goff[c] = (u32)rl * DIM + (((tid & 3) ^ ((rl >> 1) & 3)) << 3);
  }
  const u16* ebR = eb + (size_t)rowbase * DIM;

  u16 *pA = lds,             *qA = lds + 8192,  *sA = lds + 16384;
  u16 *pB = lds + 24576,     *qB = lds + 32768, *sB = lds + 40960;

  #define STAGE_A(v_, t_, c_) \
    gl_lds16(ebR + (u32)(((v_) & 15) * BK) + goff[c_], (t_) + (c_) * 4096 + w * 512)
  #define STAGE_B(v_, t_, c_) \
    gl_lds16(wb + (u32)(n0s + ((v_) >> 4)) * (BN * DIM) + (u32)(((v_) & 15) * BK) + goff[c_], \
             (t_) + (c_) * 4096 + w * 512)

  f32x4 acc[8][4];
  #pragma unroll
  for (int m = 0; m < 8; m++)
    #pragma unroll
    for (int n = 0; n < 4; n++)
      #pragma unroll
      for (int q = 0; q < 4; q++) acc[m][n][q] = 0.f;

  // prologue: stage K-steps 0 and 1 (4 chunks each, issue order = ring order)
  STAGE_A(0, pA, 0); STAGE_A(0, pA, 1); STAGE_B(0, pB, 0); STAGE_B(0, pB, 1);
  STAGE_A(1, qA, 0); STAGE_A(1, qA, 1); STAGE_B(1, qB, 0); STAGE_B(1, qB, 1);

  for (int u = 0; u < NS; u++) {
    const bool st = (u + 2 < NS);
    if (u < NS - 1) asm volatile("s_waitcnt vmcnt(4)" ::: "memory");
    else            asm volatile("s_waitcnt vmcnt(0)" ::: "memory");
    __builtin_amdgcn_s_barrier();
    asm volatile("" ::: "memory");

    bf16x8 af[8], bg[4];
    // ---- phase 1: read af[0-3] + bg[0-3]; stage A(u+2); MFMA m0-3 ----
    #pragma unroll
    for (int m = 0; m < 4; m++) af[m] = *(const bf16x8*)&pA[aoff[m]];
    #pragma unroll
    for (int n = 0; n < 4; n++) bg[n] = *(const bf16x8*)&pB[boff[n]];
    if (st) { STAGE_A(u + 2, sA, 0); STAGE_A(u + 2, sA, 1); }
    __builtin_amdgcn_s_setprio(1);
    #pragma unroll
    for (int m = 0; m < 4; m++)
      #pragma unroll
      for (int n = 0; n < 4; n++)
        acc[m][n] = __builtin_amdgcn_mfma_f32_16x16x32_bf16(af[m], bg[n], acc[m][n], 0, 0, 0);
    __builtin_amdgcn_s_setprio(0);
    __builtin_amdgcn_s_barrier();   // pacing barrier (same buffer both sides)
    asm volatile("" ::: "memory");

    // ---- phase 2: read af[4-7]; stage B(u+2); MFMA m4-7 ----
    #pragma unroll
    for (int m = 0; m < 4; m++) af[m + 4] = *(const bf16x8*)&pA[aoff[m + 4]];
    if (st) { STAGE_B(u + 2, sB, 0); STAGE_B(u + 2, sB, 1); }
    __builtin_amdgcn_s_setprio(1);
    #pragma unroll
    for (int m = 0; m < 4; m++)
      #pragma unroll
      for (int n = 0; n < 4; n++)
        acc[m + 4][n] = __builtin_amdgcn_mfma_f32_16x16x32_bf16(af[m + 4], bg[n], acc[m + 4][n], 0, 0, 0);
    __builtin_amdgcn_s_setprio(0);

    if ((u & 15) == 15) {
      // epilogue for N-tile nt: clip, exp2, sum over wave's 64 cols,
      // cross-wn merge via LDS, one psum row-partial per N-tile.
      const int nt = n0s + (u >> 4);
      #pragma unroll
      for (int m = 0; m < 8; m++) {
        #pragma unroll
        for (int q = 0; q < 4; q++) {
          float s = 0.f;
          #pragma unroll
          for (int n = 0; n < 4; n++) {
            float tc = __builtin_amdgcn_fmed3f(acc[m][n][q], CLIP_LO, CLIP_HI);
            s += __builtin_amdgcn_exp2f(__builtin_fmaf(tc, K1, -K1));
            acc[m][n][q] = 0.f;
          }
          s += __shfl_xor(s, 1, 64);
          s += __shfl_xor(s, 2, 64);
          s += __shfl_xor(s, 4, 64);
          s += __shfl_xor(s, 8, 64);
          if ((l & 15) == 0) ep[wn][wm * 128 + m * 16 + (l >> 4) * 4 + q] = s;
        }
      }
      asm volatile("s_waitcnt lgkmcnt(0)" ::: "memory");
      __builtin_amdgcn_s_barrier();
      asm volatile("" ::: "memory");
      if (l < 32) {
        int r = w * 32 + l;
        float t = ep[0][r] + ep[1][r] + ep[2][r] + ep[3][r];
        psum[(size_t)nt * N_ROWS + rowbase + r] = t;
      }
      __builtin_amdgcn_s_barrier();   // ep reads done before next tile's writes
    }

    u16* t0 = pA; pA = qA; qA = sA; sA = t0;
    u16* t1 = pB; pB = qB; qB = sB; sB = t1;
  }
  #undef STAGE_A
  #undef STAGE_B
}

// ---- per-row LSE merge + margin swap + per-block loss sums ----
__global__ void arc_finish1(const float* __restrict__ psum, const float* __restrict__ ct,
                            float* __restrict__ bl) {
  int tid = threadIdx.x;
  int row = blockIdx.x * 256 + tid;
  float S = 0.f;
  for (int p = 0; p < NT2; p++) S += psum[(size_t)p * N_ROWS + row];
  float c  = __builtin_amdgcn_fmed3f(ct[row], CLIP_LO, CLIP_HI);
  float cm = c * COSM - sqrtf(fmaxf(1.0f - c * c, 0.0f)) * SINM;
  // swap the target's no-margin term for the margin term (both vs fixed max 64)
  float S2 = S - __builtin_amdgcn_exp2f(__builtin_fmaf(c,  K1, -K1))
               + __builtin_amdgcn_exp2f(__builtin_fmaf(cm, K1, -K1));
  float loss = 64.0f + __builtin_amdgcn_logf(S2) * 0.6931471805599453f - 64.0f * cm;
  #pragma unroll
  for (int off = 32; off; off >>= 1) loss += __shfl_xor(loss, off, 64);
  __shared__ float red[4];
  if ((tid & 63) == 0) red[tid >> 6] = loss;
  __syncthreads();
  if (tid == 0) bl[blockIdx.x] = red[0] + red[1] + red[2] + red[3];
}

__global__ void arc_finish2(const float* __restrict__ bl, float* __restrict__ out) {
  if (threadIdx.x == 0) {
    float t = 0.f;
    for (int i = 0; i < N_ROWS / 256; i++) t += bl[i];
    out[0] = t * (1.0f / (float)N_ROWS);
  }
}

extern "C" void kernel_launch(void* const* d_in, const int* in_sizes, int n_in,
                              void* d_out, int out_size, void* d_ws, size_t ws_size,
                              hipStream_t stream) {
  const float* emb   = (const float*)d_in[0];
  const int*   lab   = (const int*)d_in[1];
  const float* wts   = (const float*)d_in[2];

  char* ws = (char*)d_ws;
  u16*   wb    = (u16*)(ws);
  u16*   eb    = (u16*)(ws + WB_BYTES);
  float* psum  = (float*)(ws + WB_BYTES + EB_BYTES);
  float* ct    = (float*)(ws + WB_BYTES + EB_BYTES + PS_BYTES);
  float* bl    = (float*)(ws + WB_BYTES + EB_BYTES + PS_BYTES + CT_BYTES);
  int*   lab32 = (int*)  (ws + WB_BYTES + EB_BYTES + PS_BYTES + CT_BYTES + BL_BYTES);
  int*   flag  = (int*)  (ws + WB_BYTES + EB_BYTES + PS_BYTES + CT_BYTES + BL_BYTES + LAB_BYTES);
  // total ~37.1 MiB of d_ws assumed available

  lab_detect<<<dim3(1), dim3(1024), 0, stream>>>(lab, flag);
  lab_fix<<<dim3(N_ROWS / 256), dim3(256), 0, stream>>>(lab, flag, lab32);
  prep_w<<<dim3(CPAD / 4), dim3(256), 0, stream>>>(wts, wb);
  prep_e<<<dim3((N_ROWS * DIM / 8) / 256), dim3(256), 0, stream>>>(emb, eb);
  tgt_k<<<dim3(N_ROWS / 4), dim3(256), 0, stream>>>(emb, wts, lab32, ct);
  arc_main<<<dim3(16 * NSTRIPS), dim3(512), 0, stream>>>(eb, wb, psum);
  arc_finish1<<<dim3(N_ROWS / 256), dim3(256), 0, stream>>>(psum, ct, bl);
  arc_finish2<<<dim3(1), dim3(64), 0, stream>>>(bl, (float*)d_out);
}